// Round 2
// baseline (741.417 us; speedup 1.0000x reference)
//
#include <hip/hip_runtime.h>
#include <math.h>

// Problem dims
#define S_LEN 2048
#define D_HEAD 64
#define BH 32  // BS*H = 2*16

typedef __attribute__((ext_vector_type(8))) short short8;    // 8 x bf16 bits
typedef __attribute__((ext_vector_type(16))) float f32x16;   // 32x32 MFMA acc

__device__ __forceinline__ short f2bf(float f) {
  union { float f; unsigned u; } a; a.f = f;
  unsigned u = a.u;
  unsigned r = (u + 0x7fffu + ((u >> 16) & 1u)) >> 16;   // RNE, inputs never NaN
  return (short)r;
}

// ---------------------------------------------------------------------------
// Kernel 0: transpose K [bh][64][2048] -> kT [bh][2048][64] (bf16)
//           transpose V [bh][2048][64] -> vT [bh][64][2048] (bf16)
// ---------------------------------------------------------------------------
__global__ __launch_bounds__(256) void transpose_kernel(
    const float* __restrict__ kin, const float* __restrict__ vin,
    unsigned short* __restrict__ kT, unsigned short* __restrict__ vT)
{
  __shared__ float tile[64][65];
  const int bh = blockIdx.y;
  const int bx = blockIdx.x;
  const int t  = threadIdx.x;

  const float* in; unsigned short* out;
  int in_ld, out_ld, ri, ci;
  if (blockIdx.z == 0) {
    in  = kin + (size_t)bh * D_HEAD * S_LEN;   // [64][2048]
    out = kT  + (size_t)bh * S_LEN * D_HEAD;   // [2048][64]
    in_ld = S_LEN; out_ld = D_HEAD; ri = 0; ci = bx * 64;
  } else {
    in  = vin + (size_t)bh * S_LEN * D_HEAD;   // [2048][64]
    out = vT  + (size_t)bh * D_HEAD * S_LEN;   // [64][2048]
    in_ld = D_HEAD; out_ld = S_LEN; ri = bx * 64; ci = 0;
  }

  {
    const int r  = t >> 2;
    const int c4 = (t & 3) * 16;
    const float* src = in + (size_t)(ri + r) * in_ld + ci + c4;
    #pragma unroll
    for (int i = 0; i < 4; ++i) {
      float4 f = *reinterpret_cast<const float4*>(src + i * 4);
      tile[r][c4 + i*4 + 0] = f.x;
      tile[r][c4 + i*4 + 1] = f.y;
      tile[r][c4 + i*4 + 2] = f.z;
      tile[r][c4 + i*4 + 3] = f.w;
    }
  }
  __syncthreads();
  {
    const int c  = t >> 2;
    const int r4 = (t & 3) * 16;
    union { unsigned short h[16]; uint4 q[2]; } u;
    #pragma unroll
    for (int i = 0; i < 16; ++i) u.h[i] = (unsigned short)f2bf(tile[r4 + i][c]);
    uint4* dst = reinterpret_cast<uint4*>(out + (size_t)(ci + c) * out_ld + ri + r4);
    dst[0] = u.q[0];
    dst[1] = u.q[1];
  }
}

// ---------------------------------------------------------------------------
// Kernel A: scores = (Q @ K)*scale + prev (f32), plus per-row (m,l) to ws.
// Block = 128 rows (4 waves x 32 rows), 32x32x16 MFMA.
// C layout (HW-verified): col = lane&31, row = (r&3) + 8*(r>>2) + 4*(lane>>5).
// Per store/load instruction: 2 segments x 128B (full cache lines).
// Per-lane online (m,l) for 16 row-slots; single cross-lane merge at end.
// ---------------------------------------------------------------------------
__global__ __launch_bounds__(256) void scores_kernel(
    const float* __restrict__ q, const unsigned short* __restrict__ kT,
    const float* __restrict__ prev, const float* __restrict__ scale_p,
    float* __restrict__ scores, float* __restrict__ ws_m, float* __restrict__ ws_l)
{
  const int bh   = blockIdx.y;
  const int m0   = blockIdx.x * 128;
  const int tid  = threadIdx.x;
  const int w    = tid >> 6;
  const int lane = tid & 63;
  const int l31  = lane & 31;
  const int hi   = lane >> 5;       // 0/1
  const float scale = scale_p[0];
  const int wrow = m0 + w * 32;     // wave's 32-row base

  // A-frags: row = wrow + l31, element j of chunk kk -> d = kk*16 + hi*8 + j
  short8 aq[4];
  const float* qrow = q + ((size_t)bh * S_LEN + wrow + l31) * D_HEAD;
  #pragma unroll
  for (int kk = 0; kk < 4; ++kk) {
    float4 f0 = *reinterpret_cast<const float4*>(qrow + kk*16 + hi*8);
    float4 f1 = *reinterpret_cast<const float4*>(qrow + kk*16 + hi*8 + 4);
    short8 a;
    a[0]=f2bf(f0.x); a[1]=f2bf(f0.y); a[2]=f2bf(f0.z); a[3]=f2bf(f0.w);
    a[4]=f2bf(f1.x); a[5]=f2bf(f1.y); a[6]=f2bf(f1.z); a[7]=f2bf(f1.w);
    aq[kk] = a;
  }

  float ms[16], ls[16];
  #pragma unroll
  for (int r = 0; r < 16; ++r) { ms[r] = -INFINITY; ls[r] = 0.f; }

  const unsigned short* kbase = kT + (size_t)bh * S_LEN * D_HEAD;
  const float* prow = prev   + (size_t)bh * S_LEN * S_LEN;
  float*       srow = scores + (size_t)bh * S_LEN * S_LEN;

  for (int n0 = 0; n0 < S_LEN; n0 += 64) {
    f32x16 acc[2];
    #pragma unroll
    for (int ct = 0; ct < 2; ++ct)
      #pragma unroll
      for (int r = 0; r < 16; ++r) acc[ct][r] = 0.f;

    #pragma unroll
    for (int kk = 0; kk < 4; ++kk) {
      #pragma unroll
      for (int ct = 0; ct < 2; ++ct) {
        const unsigned short* kp =
            kbase + (size_t)(n0 + ct*32 + l31) * D_HEAD + kk*16 + hi*8;
        short8 b = *reinterpret_cast<const short8*>(kp);
        acc[ct] = __builtin_amdgcn_mfma_f32_32x32x16_bf16(aq[kk], b, acc[ct], 0, 0, 0);
      }
    }

    // epilogue: scale + prev, store (128B segments), per-lane stats
    float sv0[16], sv1[16];
    #pragma unroll
    for (int r = 0; r < 16; ++r) {
      const int row = wrow + (r&3) + 8*(r>>2) + 4*hi;
      const size_t g0 = (size_t)row * S_LEN + n0 + l31;
      sv0[r] = acc[0][r] * scale + prow[g0];
      sv1[r] = acc[1][r] * scale + prow[g0 + 32];
      srow[g0]      = sv0[r];
      srow[g0 + 32] = sv1[r];
    }
    #pragma unroll
    for (int r = 0; r < 16; ++r) {
      const float nm = fmaxf(ms[r], fmaxf(sv0[r], sv1[r]));
      ls[r] = ls[r] * __expf(ms[r] - nm) + __expf(sv0[r] - nm) + __expf(sv1[r] - nm);
      ms[r] = nm;
    }
  }

  // single cross-lane merge over the 32-lane halves (masks 1..16 keep hi group)
  #pragma unroll
  for (int r = 0; r < 16; ++r) {
    float m = ms[r], l = ls[r];
    #pragma unroll
    for (int msk = 1; msk <= 16; msk <<= 1) {
      const float mo = __shfl_xor(m, msk, 64);
      const float lo = __shfl_xor(l, msk, 64);
      const float nm = fmaxf(m, mo);
      l = l * __expf(m - nm) + lo * __expf(mo - nm);
      m = nm;
    }
    if (l31 == 0) {
      const int row = wrow + (r&3) + 8*(r>>2) + 4*hi;
      ws_m[bh * S_LEN + row] = m;
      ws_l[bh * S_LEN + row] = l;
    }
  }
}

// ---------------------------------------------------------------------------
// Kernel B: weights = exp(s-m)/l (f32), O = weights @ V.
// Per 64-col tile: coalesced phase (float4 score reads / weight writes,
// 256B-per-row chunks) -> bf16 into padded LDS -> MFMA phase (A from LDS,
// B = vT from L2/LLC). 32x32x16 MFMA, acc persistent.
// ---------------------------------------------------------------------------
#define WPAD 8   // bf16 pad: row stride 72 el = 144 B (16B-aligned, bank-spread)

__global__ __launch_bounds__(256) void pv_kernel(
    const float* __restrict__ scores, const unsigned short* __restrict__ vT,
    const float* __restrict__ ws_m, const float* __restrict__ ws_l,
    float* __restrict__ weights, float* __restrict__ outO)
{
  __shared__ unsigned short wlds[128][64 + WPAD];

  const int bh   = blockIdx.y;
  const int m0   = blockIdx.x * 128;
  const int tid  = threadIdx.x;
  const int w    = tid >> 6;
  const int lane = tid & 63;
  const int l31  = lane & 31;
  const int hi   = lane >> 5;
  const int wrow = m0 + w * 32;

  // coalesced-phase mapping: thread handles rows rbase+16*i, cols cbase..cbase+3
  const int rbase = tid >> 4;        // 0..15
  const int cbase = (tid & 15) * 4;  // 0,4,...,60

  float mreg[8], rlreg[8];
  #pragma unroll
  for (int i = 0; i < 8; ++i) {
    const int row = m0 + rbase + 16*i;
    mreg[i]  = ws_m[bh * S_LEN + row];
    rlreg[i] = 1.0f / ws_l[bh * S_LEN + row];
  }

  const float* sbase = scores  + (size_t)bh * S_LEN * S_LEN;
  float*       wbase = weights + (size_t)bh * S_LEN * S_LEN;
  const unsigned short* vb = vT + (size_t)bh * D_HEAD * S_LEN;

  f32x16 acc[2];
  #pragma unroll
  for (int ct = 0; ct < 2; ++ct)
    #pragma unroll
    for (int r = 0; r < 16; ++r) acc[ct][r] = 0.f;

  for (int n0 = 0; n0 < S_LEN; n0 += 64) {
    // phase 1: coalesced softmax-finish + weights write + LDS stage
    #pragma unroll
    for (int i = 0; i < 8; ++i) {
      const int rl = rbase + 16*i;
      const size_t g = (size_t)(m0 + rl) * S_LEN + n0 + cbase;
      const float4 f = *reinterpret_cast<const float4*>(sbase + g);
      const float w0 = __expf(f.x - mreg[i]) * rlreg[i];
      const float w1 = __expf(f.y - mreg[i]) * rlreg[i];
      const float w2 = __expf(f.z - mreg[i]) * rlreg[i];
      const float w3 = __expf(f.w - mreg[i]) * rlreg[i];
      *reinterpret_cast<float4*>(wbase + g) = make_float4(w0, w1, w2, w3);
      ushort4 h;
      h.x = (unsigned short)f2bf(w0); h.y = (unsigned short)f2bf(w1);
      h.z = (unsigned short)f2bf(w2); h.w = (unsigned short)f2bf(w3);
      *reinterpret_cast<ushort4*>(&wlds[rl][cbase]) = h;
    }
    __syncthreads();

    // phase 2: MFMA (A = weights tile from LDS, B = vT)
    #pragma unroll
    for (int kk = 0; kk < 4; ++kk) {
      const short8 a = *reinterpret_cast<const short8*>(&wlds[w*32 + l31][kk*16 + hi*8]);
      #pragma unroll
      for (int ct = 0; ct < 2; ++ct) {
        const unsigned short* vp =
            vb + (size_t)(ct*32 + l31) * S_LEN + n0 + kk*16 + hi*8;
        const short8 b = *reinterpret_cast<const short8*>(vp);
        acc[ct] = __builtin_amdgcn_mfma_f32_32x32x16_bf16(a, b, acc[ct], 0, 0, 0);
      }
    }
    __syncthreads();
  }

  // epilogue: O store (2 x 128B segments per instruction)
  #pragma unroll
  for (int ct = 0; ct < 2; ++ct) {
    #pragma unroll
    for (int r = 0; r < 16; ++r) {
      const int row = wrow + (r&3) + 8*(r>>2) + 4*hi;
      outO[((size_t)bh * S_LEN + row) * D_HEAD + ct*32 + l31] = acc[ct][r];
    }
  }
}

// ---------------------------------------------------------------------------
extern "C" void kernel_launch(void* const* d_in, const int* in_sizes, int n_in,
                              void* d_out, int out_size, void* d_ws, size_t ws_size,
                              hipStream_t stream)
{
  const float* q     = (const float*)d_in[0];
  const float* kin   = (const float*)d_in[1];
  const float* vin   = (const float*)d_in[2];
  const float* prev  = (const float*)d_in[3];
  const float* scale = (const float*)d_in[4];

  float* O  = (float*)d_out;                                  // [32][2048][64]
  float* W  = O + (size_t)BH * S_LEN * D_HEAD;                // [32][2048][2048]
  float* Sc = W + (size_t)BH * S_LEN * S_LEN;                 // [32][2048][2048]

  unsigned short* kT = (unsigned short*)d_ws;
  unsigned short* vT = kT + (size_t)BH * S_LEN * D_HEAD;
  float* ws_m = (float*)(vT + (size_t)BH * S_LEN * D_HEAD);
  float* ws_l = ws_m + BH * S_LEN;

  dim3 tgrid(S_LEN / 64, BH, 2);
  hipLaunchKernelGGL(transpose_kernel, tgrid, dim3(256), 0, stream, kin, vin, kT, vT);

  dim3 grid(S_LEN / 128, BH);
  hipLaunchKernelGGL(scores_kernel, grid, dim3(256), 0, stream,
                     q, kT, prev, scale, Sc, ws_m, ws_l);
  hipLaunchKernelGGL(pv_kernel, grid, dim3(256), 0, stream,
                     Sc, vT, ws_m, ws_l, W, O);
}